// Round 9
// baseline (105.089 us; speedup 1.0000x reference)
//
#include <hip/hip_runtime.h>
#include <hip/hip_bf16.h>

#ifndef __has_builtin
#define __has_builtin(x) 0
#endif

// ---- problem constants ----
constexpr int B_ = 8, TE_ = 512, TD_ = 128, H_ = 256;
constexpr float TWO_LOG2E = 2.8853900817779268f;   // 2*log2(e)
constexpr float LOG2E = 1.4426950408889634f;

typedef float  vf2    __attribute__((ext_vector_type(2)));
typedef short  bf16x8 __attribute__((ext_vector_type(8)));
typedef float  f32x4  __attribute__((ext_vector_type(4)));

__device__ __forceinline__ float exp2_fast(float x) {
#if __has_builtin(__builtin_amdgcn_exp2f)
  return __builtin_amdgcn_exp2f(x);     // v_exp_f32 (quarter rate)
#else
  return exp2f(x);
#endif
}
__device__ __forceinline__ float rcp_fast(float x) {
#if __has_builtin(__builtin_amdgcn_rcpf)
  return __builtin_amdgcn_rcpf(x);      // v_rcp_f32 (quarter rate)
#else
  return 1.0f / x;
#endif
}
__device__ __forceinline__ vf2 fma2(vf2 a, vf2 b, vf2 c) {
#if __has_builtin(__builtin_elementwise_fma)
  return __builtin_elementwise_fma(a, b, c);   // v_pk_fma_f32
#else
  vf2 r; r.x = __fmaf_rn(a.x, b.x, c.x); r.y = __fmaf_rn(a.y, b.y, c.y); return r;
#endif
}
// split fp32 -> bf16 hi + bf16 lo (x ~= hi + lo to ~2^-16 rel)
__device__ __forceinline__ void bf16split(float x, unsigned short& hi, unsigned short& lo) {
  unsigned u = __float_as_uint(x);
  hi = (unsigned short)(u >> 16);
  float hif = __uint_as_float((unsigned)hi << 16);
  lo = (unsigned short)(__float_as_uint(x - hif) >> 16);
}

// ============== MFMA projection: ep=exp2((enc@W)*2log2e), dp=exp2((dec@U)*2log2e) ==============
// Split-bf16 (3 products). Block tile 32m x 32n, 4 waves, K chunks of 32.
// grid (160, 8) = 1280 blocks. Block (0,0) also zeroes rowsum (visible to score
// via the kernel boundary). Epilogue exp2: t = exp2(ep'+dp') = E*D in score.
__global__ __launch_bounds__(256)
void proj_mfma(const float* __restrict__ enc, const float* __restrict__ dec,
               const float* __restrict__ W, const float* __restrict__ U,
               float* __restrict__ ep, float* __restrict__ dp,
               float* __restrict__ rowsum) {
  __shared__ unsigned short Ah[32][40], Al[32][40], Bh[32][40], Bl[32][40];
  const int tid = threadIdx.x;
  if (blockIdx.x == 0 && blockIdx.y == 0) {
    float4 z = {0.f, 0.f, 0.f, 0.f};
    *(float4*)&rowsum[tid * 4] = z;      // 256 threads x 4 = 1024 rows
  }
  const int mt = blockIdx.x;
  const int n0 = blockIdx.y * 32;
  const float* A; const float* Bm; float* C; int row0;
  if (mt < 128) { A = enc; Bm = W; C = ep; row0 = mt * 32; }
  else          { A = dec; Bm = U; C = dp; row0 = (mt - 128) * 32; }
  const int w = tid >> 6, lane = tid & 63;
  const int mw = (w & 1) * 16, nw = (w >> 1) * 16;
  const int quad = lane >> 4, l16 = lane & 15;
  const int am = tid >> 3, ak = (tid & 7) * 4;
  const int bn = tid & 31, bk = (tid >> 5) * 4;

  f32x4 acc = {0.f, 0.f, 0.f, 0.f};
  for (int k0 = 0; k0 < H_; k0 += 32) {
    float4 a4 = *(const float4*)&A[(long)(row0 + am) * H_ + k0 + ak];
    unsigned short h0, l0, h1, l1, h2, l2, h3, l3;
    bf16split(a4.x, h0, l0); bf16split(a4.y, h1, l1);
    bf16split(a4.z, h2, l2); bf16split(a4.w, h3, l3);
    *(ushort4*)&Ah[am][ak] = make_ushort4(h0, h1, h2, h3);
    *(ushort4*)&Al[am][ak] = make_ushort4(l0, l1, l2, l3);
    float b0 = Bm[(long)(k0 + bk + 0) * H_ + n0 + bn];
    float b1 = Bm[(long)(k0 + bk + 1) * H_ + n0 + bn];
    float b2 = Bm[(long)(k0 + bk + 2) * H_ + n0 + bn];
    float b3 = Bm[(long)(k0 + bk + 3) * H_ + n0 + bn];
    bf16split(b0, h0, l0); bf16split(b1, h1, l1);
    bf16split(b2, h2, l2); bf16split(b3, h3, l3);
    *(ushort4*)&Bh[bn][bk] = make_ushort4(h0, h1, h2, h3);
    *(ushort4*)&Bl[bn][bk] = make_ushort4(l0, l1, l2, l3);
    __syncthreads();
    bf16x8 ah = *(const bf16x8*)&Ah[mw + l16][quad * 8];
    bf16x8 al = *(const bf16x8*)&Al[mw + l16][quad * 8];
    bf16x8 bh = *(const bf16x8*)&Bh[nw + l16][quad * 8];
    bf16x8 bl = *(const bf16x8*)&Bl[nw + l16][quad * 8];
    acc = __builtin_amdgcn_mfma_f32_16x16x32_bf16(ah, bh, acc, 0, 0, 0);
    acc = __builtin_amdgcn_mfma_f32_16x16x32_bf16(ah, bl, acc, 0, 0, 0);
    acc = __builtin_amdgcn_mfma_f32_16x16x32_bf16(al, bh, acc, 0, 0, 0);
    __syncthreads();
  }
#pragma unroll
  for (int r = 0; r < 4; ++r)
    C[(long)(row0 + mw + quad * 4 + r) * H_ + n0 + nw + l16] =
        exp2_fast(acc[r] * TWO_LOG2E);
}

// ========== score kernel: u = exp(score'), rowsum += partial (no softmax pass) ==========
// score'[b,d,e] = sum_h (-2 v_h)*rcp(1 + E[e,h]*D[d,h])  (== ref score - const shift;
// the shift cancels in u/rowsum). |score'| <= ~18 -> exp never overflows fp32, so no
// max-subtraction is needed. Tiles 32e x 16d, 256 threads (1e x 2d), grid (16,8,8).
__global__ __launch_bounds__(256)
void score_kernel(const float* __restrict__ ep, const float* __restrict__ dp,
                  const float* __restrict__ v, float* __restrict__ u,
                  float* __restrict__ rowsum) {
  __shared__ __align__(16) float eps[32][68];
  __shared__ __align__(16) float dps[16][68];
  __shared__ __align__(16) float vs[64];
  const int tid = threadIdx.x;
  const int b = blockIdx.z;
  const int e0 = blockIdx.x * 32;
  const int d0 = blockIdx.y * 16;
  const int e = tid & 31;
  const int dg = tid >> 5;
  vf2 acc0 = {0.f, 0.f}, acc1 = {0.f, 0.f};

  for (int h0 = 0; h0 < H_; h0 += 64) {
#pragma unroll
    for (int i = 0; i < 2; ++i) {
      int idx = tid + i * 256;
      int r = idx >> 4, c = (idx & 15) << 2;
      *(float4*)&eps[r][c] = *(const float4*)&ep[(long)(b * TE_ + e0 + r) * H_ + h0 + c];
    }
    {
      int r = tid >> 4, c = (tid & 15) << 2;
      *(float4*)&dps[r][c] = *(const float4*)&dp[(long)(b * TD_ + d0 + r) * H_ + h0 + c];
    }
    if (tid < 16) {
      float4 v4 = *(const float4*)&v[h0 + tid * 4];
      float4 o; o.x = -2.f * v4.x; o.y = -2.f * v4.y; o.z = -2.f * v4.z; o.w = -2.f * v4.w;
      *(float4*)&vs[tid * 4] = o;
    }
    __syncthreads();
    const vf2 one2 = {1.f, 1.f};
#pragma unroll
    for (int hh = 0; hh < 64; hh += 4) {
      float4 evf = *(const float4*)&eps[e][hh];
      float4 vvf = *(const float4*)&vs[hh];
      float4 daf = *(const float4*)&dps[dg * 2 + 0][hh];
      float4 dbf = *(const float4*)&dps[dg * 2 + 1][hh];
      vf2 ev0 = {evf.x, evf.y}, ev1 = {evf.z, evf.w};
      vf2 vv0 = {vvf.x, vvf.y}, vv1 = {vvf.z, vvf.w};
      vf2 da0 = {daf.x, daf.y}, da1 = {daf.z, daf.w};
      vf2 db0 = {dbf.x, dbf.y}, db1 = {dbf.z, dbf.w};
      vf2 t0 = ev0 * da0 + one2;   // v_pk_fma: E*D + 1
      vf2 t1 = ev1 * da1 + one2;
      vf2 u0 = ev0 * db0 + one2;
      vf2 u1 = ev1 * db1 + one2;
      vf2 r0, r1, s0, s1;
      r0.x = rcp_fast(t0.x); r0.y = rcp_fast(t0.y);
      r1.x = rcp_fast(t1.x); r1.y = rcp_fast(t1.y);
      s0.x = rcp_fast(u0.x); s0.y = rcp_fast(u0.y);
      s1.x = rcp_fast(u1.x); s1.y = rcp_fast(u1.y);
      acc0 = fma2(vv0, r0, acc0); acc0 = fma2(vv1, r1, acc0);
      acc1 = fma2(vv0, s0, acc1); acc1 = fma2(vv1, s1, acc1);
    }
    __syncthreads();
  }
  // u = exp(score'), then per-row partial sums over this block's 32 e-columns
  const float uv0 = exp2_fast((acc0.x + acc0.y) * LOG2E);
  const float uv1 = exp2_fast((acc1.x + acc1.y) * LOG2E);
  long base = ((long)b * TD_ + d0 + dg * 2) * TE_ + e0 + e;
  u[base] = uv0;
  u[base + TE_] = uv1;
  float s0 = uv0, s1 = uv1;
#pragma unroll
  for (int off = 16; off; off >>= 1) {   // xor<32: stays within the 32-lane e-group
    s0 += __shfl_xor(s0, off, 64);
    s1 += __shfl_xor(s1, off, 64);
  }
  if (e == 0) {
    const int row = b * TD_ + d0 + dg * 2;
    atomicAdd(&rowsum[row], s0);
    atomicAdd(&rowsum[row + 1], s1);
  }
}

// ========== MFMA context + attn write: p = u/rowsum; ctx = p @ enc ==========
// M=128, N=256, K=512 per batch. Block tile 32m x 32n, K chunks of 32,
// grid (4, 8, 8) = 256 blocks. A-tile is staged NORMALIZED (p), so no epilogue
// scale; n0==0 blocks write p to the attn output during staging (each element
// exactly once). Split-bf16 3-product scheme.
__global__ __launch_bounds__(256)
void ctx_mfma(const float* __restrict__ u, const float* __restrict__ rowsum,
              const float* __restrict__ enc, float* __restrict__ attn,
              float* __restrict__ ctx) {
  __shared__ unsigned short Ah[32][40], Al[32][40], Bh[32][40], Bl[32][40];
  const int tid = threadIdx.x;
  const int m0 = blockIdx.x * 32;
  const int n0 = blockIdx.y * 32;
  const int b = blockIdx.z;
  const float* A = u + ((long)b * TD_ + m0) * TE_;
  const float* E = enc + (long)b * TE_ * H_;
  const int w = tid >> 6, lane = tid & 63;
  const int mw = (w & 1) * 16, nw = (w >> 1) * 16;
  const int quad = lane >> 4, l16 = lane & 15;
  const int am = tid >> 3, ak = (tid & 7) * 4;
  const int bn = tid & 31, bk = (tid >> 5) * 4;
  const float rinv = rcp_fast(rowsum[b * TD_ + m0 + am]);
  const bool writeAttn = (n0 == 0);
  float* arow = attn + ((long)b * TD_ + m0 + am) * TE_;

  f32x4 acc = {0.f, 0.f, 0.f, 0.f};
  for (int k0 = 0; k0 < TE_; k0 += 32) {
    float4 a4 = *(const float4*)&A[(long)am * TE_ + k0 + ak];
    float4 p;
    p.x = a4.x * rinv; p.y = a4.y * rinv; p.z = a4.z * rinv; p.w = a4.w * rinv;
    if (writeAttn) *(float4*)&arow[k0 + ak] = p;   // attention-weights output
    unsigned short h0, l0, h1, l1, h2, l2, h3, l3;
    bf16split(p.x, h0, l0); bf16split(p.y, h1, l1);
    bf16split(p.z, h2, l2); bf16split(p.w, h3, l3);
    *(ushort4*)&Ah[am][ak] = make_ushort4(h0, h1, h2, h3);
    *(ushort4*)&Al[am][ak] = make_ushort4(l0, l1, l2, l3);
    float b0 = E[(long)(k0 + bk + 0) * H_ + n0 + bn];
    float b1 = E[(long)(k0 + bk + 1) * H_ + n0 + bn];
    float b2 = E[(long)(k0 + bk + 2) * H_ + n0 + bn];
    float b3 = E[(long)(k0 + bk + 3) * H_ + n0 + bn];
    bf16split(b0, h0, l0); bf16split(b1, h1, l1);
    bf16split(b2, h2, l2); bf16split(b3, h3, l3);
    *(ushort4*)&Bh[bn][bk] = make_ushort4(h0, h1, h2, h3);
    *(ushort4*)&Bl[bn][bk] = make_ushort4(l0, l1, l2, l3);
    __syncthreads();
    bf16x8 ah = *(const bf16x8*)&Ah[mw + l16][quad * 8];
    bf16x8 al = *(const bf16x8*)&Al[mw + l16][quad * 8];
    bf16x8 bh = *(const bf16x8*)&Bh[nw + l16][quad * 8];
    bf16x8 bl = *(const bf16x8*)&Bl[nw + l16][quad * 8];
    acc = __builtin_amdgcn_mfma_f32_16x16x32_bf16(ah, bh, acc, 0, 0, 0);
    acc = __builtin_amdgcn_mfma_f32_16x16x32_bf16(ah, bl, acc, 0, 0, 0);
    acc = __builtin_amdgcn_mfma_f32_16x16x32_bf16(al, bh, acc, 0, 0, 0);
    __syncthreads();
  }
#pragma unroll
  for (int r = 0; r < 4; ++r)
    ctx[((long)b * TD_ + m0 + mw + quad * 4 + r) * H_ + n0 + nw + l16] = acc[r];
}

extern "C" void kernel_launch(void* const* d_in, const int* in_sizes, int n_in,
                              void* d_out, int out_size, void* d_ws, size_t ws_size,
                              hipStream_t stream) {
  const float* enc = (const float*)d_in[0];  // [B,TE,H]
  const float* dec = (const float*)d_in[1];  // [B,TD,H]
  const float* Wa  = (const float*)d_in[2];  // [H,H]
  const float* Ua  = (const float*)d_in[3];  // [H,H]
  const float* Va  = (const float*)d_in[4];  // [H,1]

  float* out  = (float*)d_out;
  float* ctx  = out;                           // [B,TD,H]
  float* attn = out + (long)B_ * TD_ * H_;     // [B,TD,TE]

  float* ep = (float*)d_ws;                    // [B*TE,H] = exp2(proj*2log2e)
  float* dp = ep + (long)B_ * TE_ * H_;        // [B*TD,H]
  float* u  = dp + (long)B_ * TD_ * H_;        // [B,TD,TE] unnormalized weights
  float* rowsum = u + (long)B_ * TD_ * TE_;    // [B*TD] softmax denominators

  proj_mfma<<<dim3(160, 8), 256, 0, stream>>>(enc, dec, Wa, Ua, ep, dp, rowsum);
  score_kernel<<<dim3(TE_ / 32, TD_ / 16, B_), 256, 0, stream>>>(ep, dp, Va, u, rowsum);
  ctx_mfma<<<dim3(TD_ / 32, H_ / 32, B_), 256, 0, stream>>>(u, rowsum, enc, attn, ctx);
}

// Round 10
// 101.091 us; speedup vs baseline: 1.0396x; 1.0396x over previous
//
#include <hip/hip_runtime.h>
#include <hip/hip_bf16.h>

#ifndef __has_builtin
#define __has_builtin(x) 0
#endif

// ---- problem constants ----
constexpr int B_ = 8, TE_ = 512, TD_ = 128, H_ = 256;
constexpr float TWO_LOG2E = 2.8853900817779268f;   // 2*log2(e)
constexpr float LOG2E = 1.4426950408889634f;

typedef float  vf2    __attribute__((ext_vector_type(2)));
typedef short  bf16x8 __attribute__((ext_vector_type(8)));
typedef float  f32x4  __attribute__((ext_vector_type(4)));

__device__ __forceinline__ float exp2_fast(float x) {
#if __has_builtin(__builtin_amdgcn_exp2f)
  return __builtin_amdgcn_exp2f(x);     // v_exp_f32 (quarter rate)
#else
  return exp2f(x);
#endif
}
__device__ __forceinline__ float rcp_fast(float x) {
#if __has_builtin(__builtin_amdgcn_rcpf)
  return __builtin_amdgcn_rcpf(x);      // v_rcp_f32 (quarter rate)
#else
  return 1.0f / x;
#endif
}
// split fp32 -> bf16 hi + bf16 lo (x ~= hi + lo to ~2^-16 rel)
__device__ __forceinline__ void bf16split(float x, unsigned short& hi, unsigned short& lo) {
  unsigned u = __float_as_uint(x);
  hi = (unsigned short)(u >> 16);
  float hif = __uint_as_float((unsigned)hi << 16);
  lo = (unsigned short)(__float_as_uint(x - hif) >> 16);
}

// ============== MFMA projection: ep=exp2((enc@W)*2log2e), dp=exp2((dec@U)*2log2e) ==============
// Split-bf16 (3 products). Block tile 32m x 32n, 4 waves, K chunks of 32.
// grid (160, 8) = 1280 blocks. Epilogue exp2: score uses t = exp2(ep'+dp') = E*D.
__global__ __launch_bounds__(256)
void proj_mfma(const float* __restrict__ enc, const float* __restrict__ dec,
               const float* __restrict__ W, const float* __restrict__ U,
               float* __restrict__ ep, float* __restrict__ dp) {
  __shared__ unsigned short Ah[32][40], Al[32][40], Bh[32][40], Bl[32][40];
  const int tid = threadIdx.x;
  const int mt = blockIdx.x;
  const int n0 = blockIdx.y * 32;
  const float* A; const float* Bm; float* C; int row0;
  if (mt < 128) { A = enc; Bm = W; C = ep; row0 = mt * 32; }
  else          { A = dec; Bm = U; C = dp; row0 = (mt - 128) * 32; }
  const int w = tid >> 6, lane = tid & 63;
  const int mw = (w & 1) * 16, nw = (w >> 1) * 16;
  const int quad = lane >> 4, l16 = lane & 15;
  const int am = tid >> 3, ak = (tid & 7) * 4;
  const int bn = tid & 31, bk = (tid >> 5) * 4;

  f32x4 acc = {0.f, 0.f, 0.f, 0.f};
  for (int k0 = 0; k0 < H_; k0 += 32) {
    float4 a4 = *(const float4*)&A[(long)(row0 + am) * H_ + k0 + ak];
    unsigned short h0, l0, h1, l1, h2, l2, h3, l3;
    bf16split(a4.x, h0, l0); bf16split(a4.y, h1, l1);
    bf16split(a4.z, h2, l2); bf16split(a4.w, h3, l3);
    *(ushort4*)&Ah[am][ak] = make_ushort4(h0, h1, h2, h3);
    *(ushort4*)&Al[am][ak] = make_ushort4(l0, l1, l2, l3);
    float b0 = Bm[(long)(k0 + bk + 0) * H_ + n0 + bn];
    float b1 = Bm[(long)(k0 + bk + 1) * H_ + n0 + bn];
    float b2 = Bm[(long)(k0 + bk + 2) * H_ + n0 + bn];
    float b3 = Bm[(long)(k0 + bk + 3) * H_ + n0 + bn];
    bf16split(b0, h0, l0); bf16split(b1, h1, l1);
    bf16split(b2, h2, l2); bf16split(b3, h3, l3);
    *(ushort4*)&Bh[bn][bk] = make_ushort4(h0, h1, h2, h3);
    *(ushort4*)&Bl[bn][bk] = make_ushort4(l0, l1, l2, l3);
    __syncthreads();
    bf16x8 ah = *(const bf16x8*)&Ah[mw + l16][quad * 8];
    bf16x8 al = *(const bf16x8*)&Al[mw + l16][quad * 8];
    bf16x8 bh = *(const bf16x8*)&Bh[nw + l16][quad * 8];
    bf16x8 bl = *(const bf16x8*)&Bl[nw + l16][quad * 8];
    acc = __builtin_amdgcn_mfma_f32_16x16x32_bf16(ah, bh, acc, 0, 0, 0);
    acc = __builtin_amdgcn_mfma_f32_16x16x32_bf16(ah, bl, acc, 0, 0, 0);
    acc = __builtin_amdgcn_mfma_f32_16x16x32_bf16(al, bh, acc, 0, 0, 0);
    __syncthreads();
  }
#pragma unroll
  for (int r = 0; r < 4; ++r)
    C[(long)(row0 + mw + quad * 4 + r) * H_ + n0 + nw + l16] =
        exp2_fast(acc[r] * TWO_LOG2E);
}

// ================= score kernel: pairwise-rcp, t = E*D =================
// sc_part[hs][b,d,e] = sum_h (-2 v_h)*rcp(1+E*D)  (h-split halves; const-shifted).
// Pairwise combine: v0/w0 + v1/w1 = (v0*w1 + v1*w0) * rcp(w0*w1), w = 1+E*D.
// Exact algebra; w <= ~2^30 so w0*w1 cannot overflow fp32.
// Tiles 32e x 16d, 256 threads (1e x 2d), grid (16,8,16) = 2048 blocks (8/CU).
__global__ __launch_bounds__(256)
void score_kernel(const float* __restrict__ ep, const float* __restrict__ dp,
                  const float* __restrict__ v, float* __restrict__ sc) {
  __shared__ __align__(16) float eps[32][68];
  __shared__ __align__(16) float dps[16][68];
  __shared__ __align__(16) float vs[64];
  const int tid = threadIdx.x;
  const int bz = blockIdx.z;
  const int b = bz >> 1;
  const int h_lo = (bz & 1) * 128;
  const int e0 = blockIdx.x * 32;
  const int d0 = blockIdx.y * 16;
  const int e = tid & 31;
  const int dg = tid >> 5;
  float acc0 = 0.f, acc1 = 0.f;

  for (int h0 = h_lo; h0 < h_lo + 128; h0 += 64) {
#pragma unroll
    for (int i = 0; i < 2; ++i) {
      int idx = tid + i * 256;
      int r = idx >> 4, c = (idx & 15) << 2;
      *(float4*)&eps[r][c] = *(const float4*)&ep[(long)(b * TE_ + e0 + r) * H_ + h0 + c];
    }
    {
      int r = tid >> 4, c = (tid & 15) << 2;
      *(float4*)&dps[r][c] = *(const float4*)&dp[(long)(b * TD_ + d0 + r) * H_ + h0 + c];
    }
    if (tid < 16) {
      float4 v4 = *(const float4*)&v[h0 + tid * 4];
      float4 o; o.x = -2.f * v4.x; o.y = -2.f * v4.y; o.z = -2.f * v4.z; o.w = -2.f * v4.w;
      *(float4*)&vs[tid * 4] = o;
    }
    __syncthreads();
    const vf2 one2 = {1.f, 1.f};
#pragma unroll
    for (int hh = 0; hh < 64; hh += 4) {
      float4 evf = *(const float4*)&eps[e][hh];          // E
      float4 vvf = *(const float4*)&vs[hh];              // -2v
      float4 daf = *(const float4*)&dps[dg * 2 + 0][hh]; // D row 0
      float4 dbf = *(const float4*)&dps[dg * 2 + 1][hh]; // D row 1
      vf2 ev0 = {evf.x, evf.y}, ev1 = {evf.z, evf.w};
      vf2 da0 = {daf.x, daf.y}, da1 = {daf.z, daf.w};
      vf2 db0 = {dbf.x, dbf.y}, db1 = {dbf.z, dbf.w};
      // w = 1 + E*D (packed)
      vf2 wa0 = ev0 * da0 + one2;   // d-row0, h pair (0,1)
      vf2 wa1 = ev1 * da1 + one2;   // d-row0, h pair (2,3)
      vf2 wb0 = ev0 * db0 + one2;   // d-row1, h pair (0,1)
      vf2 wb1 = ev1 * db1 + one2;   // d-row1, h pair (2,3)
      // pairwise: acc += (v0*w.y + v1*w.x) * rcp(w.x*w.y)
      float na0 = __fmaf_rn(vvf.x, wa0.y, vvf.y * wa0.x);
      float na1 = __fmaf_rn(vvf.z, wa1.y, vvf.w * wa1.x);
      float nb0 = __fmaf_rn(vvf.x, wb0.y, vvf.y * wb0.x);
      float nb1 = __fmaf_rn(vvf.z, wb1.y, vvf.w * wb1.x);
      float ra0 = rcp_fast(wa0.x * wa0.y);
      float ra1 = rcp_fast(wa1.x * wa1.y);
      float rb0 = rcp_fast(wb0.x * wb0.y);
      float rb1 = rcp_fast(wb1.x * wb1.y);
      acc0 = __fmaf_rn(na0, ra0, acc0);
      acc0 = __fmaf_rn(na1, ra1, acc0);
      acc1 = __fmaf_rn(nb0, rb0, acc1);
      acc1 = __fmaf_rn(nb1, rb1, acc1);
    }
    __syncthreads();
  }
  long base = ((long)(bz & 1) * B_ * TD_ + (long)b * TD_ + d0 + dg * 2) * TE_ + e0 + e;
  sc[base] = acc0;
  sc[base + TE_] = acc1;
}

// ====== softmax: attn row = softmax(sc_half0 + sc_half1), one wave per row ======
__global__ __launch_bounds__(64)
void softmax_kernel(const float* __restrict__ sc, float* __restrict__ attn) {
  const long row = blockIdx.x;
  const float* p0 = sc + row * TE_;
  const float* p1 = sc + ((long)B_ * TD_ + row) * TE_;
  float* pout = attn + row * TE_;
  const int t = threadIdx.x;
  float x[8];
  float m = -1e30f;
#pragma unroll
  for (int k = 0; k < 8; ++k) {
    x[k] = p0[t + 64 * k] + p1[t + 64 * k];
    m = fmaxf(m, x[k]);
  }
#pragma unroll
  for (int off = 32; off; off >>= 1) m = fmaxf(m, __shfl_xor(m, off, 64));
  float s = 0.f;
#pragma unroll
  for (int k = 0; k < 8; ++k) { x[k] = exp2_fast((x[k] - m) * LOG2E); s += x[k]; }
#pragma unroll
  for (int off = 32; off; off >>= 1) s += __shfl_xor(s, off, 64);
  const float r = rcp_fast(s);
#pragma unroll
  for (int k = 0; k < 8; ++k) pout[t + 64 * k] = x[k] * r;
}

// ================= MFMA context: ctx[b] = attn[b] @ enc[b] =================
// M=128, N=256, K=512 per batch. Block tile 32m x 32n, K chunks of 32.
// grid (4, 8, 8) = 256 blocks. Split-bf16 3-product scheme.
__global__ __launch_bounds__(256)
void ctx_mfma(const float* __restrict__ attn, const float* __restrict__ enc,
              float* __restrict__ ctx) {
  __shared__ unsigned short Ah[32][40], Al[32][40], Bh[32][40], Bl[32][40];
  const int tid = threadIdx.x;
  const int m0 = blockIdx.x * 32;
  const int n0 = blockIdx.y * 32;
  const int b = blockIdx.z;
  const float* A = attn + (long)b * TD_ * TE_;
  const float* E = enc + (long)b * TE_ * H_;
  const int w = tid >> 6, lane = tid & 63;
  const int mw = (w & 1) * 16, nw = (w >> 1) * 16;
  const int quad = lane >> 4, l16 = lane & 15;
  const int am = tid >> 3, ak = (tid & 7) * 4;
  const int bn = tid & 31, bk = (tid >> 5) * 4;

  f32x4 acc = {0.f, 0.f, 0.f, 0.f};
  for (int k0 = 0; k0 < TE_; k0 += 32) {
    float4 a4 = *(const float4*)&A[(long)(m0 + am) * TE_ + k0 + ak];
    unsigned short h0, l0, h1, l1, h2, l2, h3, l3;
    bf16split(a4.x, h0, l0); bf16split(a4.y, h1, l1);
    bf16split(a4.z, h2, l2); bf16split(a4.w, h3, l3);
    *(ushort4*)&Ah[am][ak] = make_ushort4(h0, h1, h2, h3);
    *(ushort4*)&Al[am][ak] = make_ushort4(l0, l1, l2, l3);
    float b0 = E[(long)(k0 + bk + 0) * H_ + n0 + bn];
    float b1 = E[(long)(k0 + bk + 1) * H_ + n0 + bn];
    float b2 = E[(long)(k0 + bk + 2) * H_ + n0 + bn];
    float b3 = E[(long)(k0 + bk + 3) * H_ + n0 + bn];
    bf16split(b0, h0, l0); bf16split(b1, h1, l1);
    bf16split(b2, h2, l2); bf16split(b3, h3, l3);
    *(ushort4*)&Bh[bn][bk] = make_ushort4(h0, h1, h2, h3);
    *(ushort4*)&Bl[bn][bk] = make_ushort4(l0, l1, l2, l3);
    __syncthreads();
    bf16x8 ah = *(const bf16x8*)&Ah[mw + l16][quad * 8];
    bf16x8 al = *(const bf16x8*)&Al[mw + l16][quad * 8];
    bf16x8 bh = *(const bf16x8*)&Bh[nw + l16][quad * 8];
    bf16x8 bl = *(const bf16x8*)&Bl[nw + l16][quad * 8];
    acc = __builtin_amdgcn_mfma_f32_16x16x32_bf16(ah, bh, acc, 0, 0, 0);
    acc = __builtin_amdgcn_mfma_f32_16x16x32_bf16(ah, bl, acc, 0, 0, 0);
    acc = __builtin_amdgcn_mfma_f32_16x16x32_bf16(al, bh, acc, 0, 0, 0);
    __syncthreads();
  }
#pragma unroll
  for (int r = 0; r < 4; ++r)
    ctx[((long)b * TD_ + m0 + mw + quad * 4 + r) * H_ + n0 + nw + l16] = acc[r];
}

extern "C" void kernel_launch(void* const* d_in, const int* in_sizes, int n_in,
                              void* d_out, int out_size, void* d_ws, size_t ws_size,
                              hipStream_t stream) {
  const float* enc = (const float*)d_in[0];  // [B,TE,H]
  const float* dec = (const float*)d_in[1];  // [B,TD,H]
  const float* Wa  = (const float*)d_in[2];  // [H,H]
  const float* Ua  = (const float*)d_in[3];  // [H,H]
  const float* Va  = (const float*)d_in[4];  // [H,1]

  float* out  = (float*)d_out;
  float* ctx  = out;                           // [B,TD,H]
  float* attn = out + (long)B_ * TD_ * H_;     // [B,TD,TE]

  float* ep = (float*)d_ws;                    // [B*TE,H] = exp2(proj*2log2e)
  float* dp = ep + (long)B_ * TE_ * H_;        // [B*TD,H]
  float* sc = dp + (long)B_ * TD_ * H_;        // [2][B,TD,TE] h-split partials

  proj_mfma<<<dim3(160, 8), 256, 0, stream>>>(enc, dec, Wa, Ua, ep, dp);
  score_kernel<<<dim3(TE_ / 32, TD_ / 16, 2 * B_), 256, 0, stream>>>(ep, dp, Va, sc);
  softmax_kernel<<<dim3(B_ * TD_), 64, 0, stream>>>(sc, attn);
  ctx_mfma<<<dim3(TD_ / 32, H_ / 32, B_), 256, 0, stream>>>(attn, enc, ctx);
}